// Round 15
// baseline (167.251 us; speedup 1.0000x reference)
//
#include <hip/hip_runtime.h>

typedef short s16x8 __attribute__((ext_vector_type(8)));
typedef float f32x4 __attribute__((ext_vector_type(4)));
typedef float f32x16 __attribute__((ext_vector_type(16)));
typedef unsigned int u32x4 __attribute__((ext_vector_type(4)));

__device__ __forceinline__ unsigned short f2bf(float f) {
    unsigned int u = __float_as_uint(f);
    u += 0x7fff + ((u >> 16) & 1);   // RNE
    return (unsigned short)(u >> 16);
}
__device__ __forceinline__ float bf2f(unsigned short h) {
    return __uint_as_float(((unsigned int)h) << 16);
}
__device__ __forceinline__ unsigned pack2bf(float lo, float hi) {
    return (unsigned)f2bf(lo) | ((unsigned)f2bf(hi) << 16);   // RNE both halves
}
__device__ __forceinline__ f32x4 mfma16(s16x8 a, s16x8 b, f32x4 c) {
    return __builtin_amdgcn_mfma_f32_16x16x32_bf16(a, b, c, 0, 0, 0);
}
__device__ __forceinline__ f32x16 mfma32(s16x8 a, s16x8 b, f32x16 c) {
    return __builtin_amdgcn_mfma_f32_32x32x16_bf16(a, b, c, 0, 0, 0);
}
__device__ __forceinline__ void async16(const void* g, void* l) {
    __builtin_amdgcn_global_load_lds(
        (const __attribute__((address_space(1))) void*)g,
        (__attribute__((address_space(3))) void*)l, 16, 0, 0);
}

#define ROPE_C (-13.287712379549449f / 32.0f)

// ---------------------------------------------------------------------------
// fp32 -> bf16: x -> xb, wq|wk|wv -> wqkvb, wp -> wpb.
// ---------------------------------------------------------------------------
__global__ __launch_bounds__(256) void convert_all(
    const float* __restrict__ x,  const float* __restrict__ wq,
    const float* __restrict__ wk, const float* __restrict__ wv,
    const float* __restrict__ wp,
    unsigned short* __restrict__ xb, unsigned short* __restrict__ wqkvb,
    unsigned short* __restrict__ wpb)
{
    const size_t XN = 2048u * 1024u, WN = 1024u * 1024u;
    size_t e = ((size_t)blockIdx.x * 256 + threadIdx.x) * 4;
    const float* s; unsigned short* d;
    if (e < XN)                { s = x  + e;               d = xb    + e; }
    else if (e < XN + WN)      { s = wq + (e - XN);        d = wqkvb + (e - XN); }
    else if (e < XN + 2 * WN)  { s = wk + (e - XN - WN);   d = wqkvb + (e - XN); }
    else if (e < XN + 3 * WN)  { s = wv + (e - XN - 2*WN); d = wqkvb + (e - XN); }
    else                       { s = wp + (e - XN - 3*WN); d = wpb   + (e - XN - 3*WN); }
    float4 v = *(const float4*)s;
    ushort4 o;
    o.x = f2bf(v.x); o.y = f2bf(v.y); o.z = f2bf(v.z); o.w = f2bf(v.w);
    *(ushort4*)d = o;
}

// ---------------------------------------------------------------------------
// bf16 GEMM (m97 structure): C = A[M x 1024] * B[N x 1024]^T.
// BM x BN tile, 4 waves (2x2), wave tile (BM/2)x(BN/2), global_load_lds.
// 1D grid, XCD-aware decode (R11, neutral; kept):
//   bx = (bid&7)*CX + (bid>>3)%CX ; by = (bid>>3)/CX ; CX = GX/8.
//
// R15: BK templated, set to 128 — halves barrier count (16->8 drain pairs),
// doubles MFMA-per-stall. LDS: qkv 48KB (3 blocks/CU = its grid limit),
// proj 32KB (5-cap >= its 2). m132's BK=128 regression was the 128˛ tile's
// 64KB LDS occupancy cliff — does not apply at these tiles.
// k-accumulation order (k0 outer, ks inner) remains strictly increasing k
// -> bit-identical results vs BK=64.
// Staging: one async16 wave-load = 512 shorts = (512/BK) rows x BK cols;
// srow = lane/(BK/8), scol = (lane%(BK/8))*8; LDS dest j*512 contiguous
// (row-major [row][BK]) matches DMA's lane*16B linear layout.
//
// *** RoPE binding order IS CORRECT AS WRITTEN — do not "fix" it. ***
// __sincosf(ang,&c,&s) binds c=sin(ang), s=cos(ang); the update is
// R(theta - pi/2) — reference rotation composed with a CONSTANT 90-degree
// rotation. Applied identically to q and k, the relative rotation
// R(th_n - th_m) (all logits see) matches the reference exactly.
// Binding sin-first gives the INVERSE relative rotation (R4 fail, 2.9e-2).
//
// Q-prescale: q section (n0<1024) scaled by 0.125 = 2^-3 (exact in bf16 ->
// attn exp argument BIT-IDENTICAL); removes *0.125f from attn hot loop.
// (R9/R10: transposed-V epilogue FAILED twice — abandoned.)
// NOTE (R3): 128x128 tile starves the grid at this shape — 64x128 is right.
// ---------------------------------------------------------------------------
template<int BM, int BN, int BK, int C32, int ROPE, int GX>
__global__ __launch_bounds__(256) void gemm_mfma(
    const unsigned short* __restrict__ A,
    const unsigned short* __restrict__ B,
    void* __restrict__ C, int Ntot)
{
    constexpr int MT = BM / 32, NT = BN / 32;
    constexpr int CX = GX / 8;
    constexpr int RPL = 512 / BK;            // rows per wave-load
    constexpr int LA  = BM / RPL;            // wave-loads for A per k-step
    constexpr int LB  = BN / RPL;
    __shared__ unsigned short As[BM * BK];
    __shared__ unsigned short Bs[BN * BK];

    const int bid  = blockIdx.x;
    const int bx   = (bid & 7) * CX + ((bid >> 3) % CX);
    const int by   = (bid >> 3) / CX;

    const int tid  = threadIdx.x;
    const int wave = tid >> 6, lane = tid & 63;
    const int l16  = lane & 15, quad = lane >> 4;
    const int m0   = by * BM, n0 = bx * BN;
    const int wm   = (wave & 1) * (BM / 2), wn = (wave >> 1) * (BN / 2);

    const int srow = lane / (BK / 8);        // 0..RPL-1
    const int scol = (lane % (BK / 8)) * 8;  // 0..BK-8

    f32x4 acc[MT][NT] = {};

    for (int k0 = 0; k0 < 1024; k0 += BK) {
        #pragma unroll
        for (int i = 0; i < LA / 4; i++) {
            int j = wave * (LA / 4) + i;
            async16(A + (size_t)(m0 + j * RPL + srow) * 1024 + k0 + scol, &As[j * 512]);
        }
        #pragma unroll
        for (int i = 0; i < LB / 4; i++) {
            int j = wave * (LB / 4) + i;
            async16(B + (size_t)(n0 + j * RPL + srow) * 1024 + k0 + scol, &Bs[j * 512]);
        }
        __syncthreads();

        #pragma unroll
        for (int ks = 0; ks < BK / 32; ks++) {
            s16x8 af[MT], bfr[NT];
            #pragma unroll
            for (int mt = 0; mt < MT; mt++)
                af[mt] = *(const s16x8*)&As[(wm + mt * 16 + l16) * BK + ks * 32 + quad * 8];
            #pragma unroll
            for (int nt = 0; nt < NT; nt++)
                bfr[nt] = *(const s16x8*)&Bs[(wn + nt * 16 + l16) * BK + ks * 32 + quad * 8];
            #pragma unroll
            for (int mt = 0; mt < MT; mt++)
                #pragma unroll
                for (int nt = 0; nt < NT; nt++)
                    acc[mt][nt] = mfma16(af[mt], bfr[nt], acc[mt][nt]);
        }
        __syncthreads();
    }

    // Fused RoPE on q/k sections (in-register, fp32, before bf16 store)
    if constexpr (ROPE) {
        if (n0 < 2048) {
            const float sc = (n0 < 1024) ? 0.125f : 1.0f;   // Q-prescale
            #pragma unroll
            for (int mt = 0; mt < MT; mt++)
                #pragma unroll
                for (int r = 0; r < 4; r++) {
                    int m = m0 + wm + mt * 16 + quad * 4 + r;   // token
                    #pragma unroll
                    for (int nt = 0; nt < 2; nt++) {
                        int i = nt * 16 + l16;                  // 0..31 in head
                        float ang = (float)m * exp2f((float)i * ROPE_C);
                        float c, s;
                        __sincosf(ang, &c, &s);   // c=sin, s=cos — see header note
                        c *= sc; s *= sc;
                        float e0 = acc[mt][nt][r], e1 = acc[mt][nt + 2][r];
                        acc[mt][nt][r]     = e0 * c + e1 * s;
                        acc[mt][nt + 2][r] = e1 * c - e0 * s;
                    }
                }
        }
    }

    // C/D layout: col = lane&15, row = quad*4 + reg
    #pragma unroll
    for (int mt = 0; mt < MT; mt++)
        #pragma unroll
        for (int nt = 0; nt < NT; nt++)
            #pragma unroll
            for (int r = 0; r < 4; r++) {
                int m = m0 + wm + mt * 16 + quad * 4 + r;
                int n = n0 + wn + nt * 16 + l16;
                size_t idx = (size_t)m * Ntot + n;
                if (C32) ((float*)C)[idx] = acc[mt][nt][r];
                else     ((unsigned short*)C)[idx] = f2bf(acc[mt][nt][r]);
            }
}

// ---------------------------------------------------------------------------
// Split-K flash attention, 32x32x16 MFMA, operand-swapped QK (verified r12).
// 1024 blocks, XCD-swizzled 1D grid (R8-proven): 16 q-blocks sharing one
// (head,ksplit) slice -> same XCD -> per-XCD L2 working set ~1MB << 4MB.
// K via global_load_lds (R12): async DMA, dbuf, linear dest + pre-swizzled
// GLOBAL source chunk (l&7)^(l>>3), reads XOR the same — rule #21.
// V via prefetched reg-gather (R13): issue V(t+1) before compute(t), pinned
// by sched_barrier(0); commit after barrier A (its vmcnt-drain covers it).
// P never touches LDS (T12). f2bf RNE mandatory (cvt_pk truncates, R2).
// Q pre-scaled by 0.125 in qkv GEMM. T5 setprio kept (neutral).
// ---------------------------------------------------------------------------
__global__ __launch_bounds__(256, 4) void attn_part(
    const unsigned short* __restrict__ qkv,
    unsigned short* __restrict__ Opart, float* __restrict__ Lpart)
{
    const int bid    = blockIdx.x;
    const int member = (bid >> 3) & 15;
    const int slice  = (bid & 7) + 8 * (bid >> 7);
    const int h  = slice & 15;
    const int ks = slice >> 4;
    const int q0 = member * 128;

    const int tid  = threadIdx.x;
    const int wave = tid >> 6, lane = tid & 63;
    const int l32  = lane & 31, half = lane >> 5;

    __shared__ unsigned short Ks[2][64][64];   // [buf][key][chunk-swizzled d]
    __shared__ unsigned short Vt[64][72];      // [d][key] pad-72

    const int srow8 = lane >> 3;                 // 0..7
    const int csw   = ((lane & 7) ^ srow8) * 8;  // pre-swizzled source chunk

    auto stageK = [&](int t, int p) {
        const int kt = ks * 512 + t * 64;
        #pragma unroll
        for (int i = 0; i < 2; i++) {
            int rb = wave * 2 + i;               // row-block 0..7
            async16(qkv + (size_t)(kt + rb * 8 + srow8) * 3072 + 1024 + h * 64 + csw,
                    &Ks[p][rb * 8][0]);
        }
    };

    // V gather across all 256 threads: 2 keys x 8 d-elements each
    const int vg  = tid & 31;                    // key-pair index (keys 2vg, 2vg+1)
    const int vd0 = (tid >> 5) * 8;              // 8-d block
    uint4 vr0, vr1;
    auto issueV = [&](int t) {
        const unsigned short* gv = qkv + (size_t)(ks * 512 + t * 64 + 2 * vg) * 3072
                                       + 2048 + h * 64 + vd0;
        vr0 = *(const uint4*)gv;
        vr1 = *(const uint4*)(gv + 3072);
    };
    auto commitV = [&]() {
        unsigned short a0[8], a1[8];
        *(uint4*)a0 = vr0; *(uint4*)a1 = vr1;
        #pragma unroll
        for (int d = 0; d < 8; d++) {
            ushort2 w; w.x = a0[d]; w.y = a1[d];
            *(ushort2*)&Vt[vd0 + d][2 * vg] = w;  // 2-way bank alias (free, m136)
        }
    };

    stageK(0, 0);                                // K-DMA(0) in flight
    issueV(0);

    const unsigned short* qp = qkv + (size_t)(q0 + wave * 32 + l32) * 3072 + h * 64 + half * 8;
    s16x8 qb[4];
    #pragma unroll
    for (int c = 0; c < 4; c++)
        qb[c] = *(const s16x8*)(qp + c * 16);

    commitV();                                   // auto-waits V(0) loads
    f32x16 o0 = {}, o1 = {};
    float lsum = 0.f;

    __syncthreads();                             // Ks[0] + Vt(0) ready

    for (int t = 0; t < 8; t++) {
        const int p = t & 1;
        if (t < 7) {
            stageK(t + 1, p ^ 1);                // async DMA under compute(t)
            issueV(t + 1);                       // reg loads under compute(t)
            __builtin_amdgcn_sched_barrier(0);   // pin: no sinking past here
        }

        #pragma unroll
        for (int g = 0; g < 2; g++) {
            f32x16 s = {};
            __builtin_amdgcn_s_setprio(1);
            #pragma unroll
            for (int c = 0; c < 4; c++) {
                int row = g * 32 + l32;
                int ch  = ((c * 2 + half) ^ (row & 7)) * 8;   // swizzled read
                s16x8 ka = *(const s16x8*)&Ks[p][row][ch];
                s = mfma32(ka, qb[c], s);
            }
            __builtin_amdgcn_s_setprio(0);
            #pragma unroll
            for (int f = 0; f < 2; f++) {
                float e[8];
                #pragma unroll
                for (int j = 0; j < 8; j++) {
                    e[j] = __expf(s[8 * f + j]);   // scale folded into Q
                    lsum += e[j];
                }
                // RNE-packed pairs (bit-identical P to LDS baseline)
                unsigned w0 = pack2bf(e[0], e[1]);   // lo0
                unsigned w1 = pack2bf(e[2], e[3]);   // lo1
                unsigned w2 = pack2bf(e[4], e[5]);   // hi0
                unsigned w3 = pack2bf(e[6], e[7]);   // hi1
                // DST=lo, SRC=hi: dst'=word0/1, src'=word2/3
                asm("v_permlane32_swap_b32 %0, %1" : "+v"(w0), "+v"(w2));
                asm("v_permlane32_swap_b32 %0, %1" : "+v"(w1), "+v"(w3));
                u32x4 wv; wv.x = w0; wv.y = w1; wv.z = w2; wv.w = w3;
                s16x8 pa = __builtin_bit_cast(s16x8, wv);
                const int c = 2 * g + f;
                s16x8 v0 = *(const s16x8*)&Vt[l32][c * 16 + half * 8];
                s16x8 v1 = *(const s16x8*)&Vt[32 + l32][c * 16 + half * 8];
                __builtin_amdgcn_s_setprio(1);
                o0 = mfma32(pa, v0, o0);
                o1 = mfma32(pa, v1, o1);
                __builtin_amdgcn_s_setprio(0);
            }
        }

        __syncthreads();          // (A) all read Vt(t); drains K-DMA + V-loads
        if (t < 7) {
            commitV();            // Vt(t+1), no extra wait needed
            __syncthreads();      // (B) Vt(t+1) visible to all
        }
    }

    lsum += __shfl_xor(lsum, 32, 64);

    const int mq = q0 + wave * 32;
    unsigned short* opBase = Opart + (size_t)ks * 2048 * 1024;
    #pragma unroll
    for (int r = 0; r < 16; r++) {
        int qr = (r & 3) + 8 * (r >> 2) + 4 * half;
        unsigned short* op = opBase + (size_t)(mq + qr) * 1024 + h * 64;
        op[l32]      = f2bf(o0[r]);
        op[32 + l32] = f2bf(o1[r]);
    }
    if (half == 0)
        Lpart[((size_t)ks * 2048 + mq + l32) * 16 + h] = lsum;
}

// ---------------------------------------------------------------------------
// Combine 4 bf16 split-K partials: ab = (sum n_i) / (sum l_i), bf16.
// ---------------------------------------------------------------------------
__global__ __launch_bounds__(256) void combine(
    const unsigned short* __restrict__ Opart, const float* __restrict__ Lpart,
    unsigned short* __restrict__ ab)
{
    size_t e = ((size_t)blockIdx.x * 256 + threadIdx.x) * 4;
    int tok = (int)(e >> 10);
    int h = (int)((e & 1023) >> 6);
    float l = 0.f;
    #pragma unroll
    for (int s = 0; s < 4; s++)
        l += Lpart[((size_t)s * 2048 + tok) * 16 + h];
    float inv = 1.0f / l;
    float a0 = 0.f, a1 = 0.f, a2 = 0.f, a3 = 0.f;
    #pragma unroll
    for (int s = 0; s < 4; s++) {
        ushort4 n = *(const ushort4*)(Opart + (size_t)s * 2048 * 1024 + e);
        a0 += bf2f(n.x); a1 += bf2f(n.y); a2 += bf2f(n.z); a3 += bf2f(n.w);
    }
    ushort4 w;
    w.x = f2bf(a0 * inv);
    w.y = f2bf(a1 * inv);
    w.z = f2bf(a2 * inv);
    w.w = f2bf(a3 * inv);
    *(ushort4*)(ab + e) = w;
}

extern "C" void kernel_launch(void* const* d_in, const int* in_sizes, int n_in,
                              void* d_out, int out_size, void* d_ws, size_t ws_size,
                              hipStream_t stream)
{
    const float* x  = (const float*)d_in[0];
    const float* wq = (const float*)d_in[1];
    const float* wk = (const float*)d_in[2];
    const float* wv = (const float*)d_in[3];
    const float* wp = (const float*)d_in[4];

    unsigned short* xb    = (unsigned short*)d_ws;        // 2M shorts
    unsigned short* wqkvb = xb    + 2u * 1024 * 1024;     // 3M
    unsigned short* wpb   = wqkvb + 3u * 1024 * 1024;     // 1M
    unsigned short* qkv   = wpb   + 1u * 1024 * 1024;     // 6M
    unsigned short* ab    = qkv   + 2048u * 3072;         // 2M
    unsigned short* Opart = ab    + 2u * 1024 * 1024;     // 4 x 2048 x 1024 bf16
    float* Lpart = (float*)(Opart + 4u * 2048 * 1024);    // 4 x 2048 x 16 fp32

    convert_all<<<6144, 256, 0, stream>>>(x, wq, wk, wv, wp, xb, wqkvb, wpb);
    // qkv GEMM with fused RoPE: 64x128 tile, BK=128 (48KB LDS, 3 blocks/CU),
    // 1D XCD-swizzled grid of 768
    gemm_mfma<64, 128, 128, 0, 1, 24><<<768, 256, 0, stream>>>(
        xb, wqkvb, qkv, 3072);
    // attn: 1D XCD-swizzled grid; K via swizzled-source DMA dbuf,
    // V via prefetched reg-gather (sched_barrier-pinned)
    attn_part<<<1024, 256, 0, stream>>>(qkv, Opart, Lpart);
    combine<<<2048, 256, 0, stream>>>(Opart, Lpart, ab);
    // proj: 64x64 tile, BK=128 (32KB LDS), 1D XCD-swizzled grid of 512
    gemm_mfma<64, 64, 128, 1, 0, 16><<<512, 256, 0, stream>>>(
        ab, wpb, d_out, 1024);
}

// Round 16
// 149.851 us; speedup vs baseline: 1.1161x; 1.1161x over previous
//
#include <hip/hip_runtime.h>

typedef short s16x8 __attribute__((ext_vector_type(8)));
typedef float f32x4 __attribute__((ext_vector_type(4)));
typedef float f32x16 __attribute__((ext_vector_type(16)));
typedef unsigned int u32x4 __attribute__((ext_vector_type(4)));

__device__ __forceinline__ unsigned short f2bf(float f) {
    unsigned int u = __float_as_uint(f);
    u += 0x7fff + ((u >> 16) & 1);   // RNE
    return (unsigned short)(u >> 16);
}
__device__ __forceinline__ float bf2f(unsigned short h) {
    return __uint_as_float(((unsigned int)h) << 16);
}
__device__ __forceinline__ unsigned pack2bf(float lo, float hi) {
    return (unsigned)f2bf(lo) | ((unsigned)f2bf(hi) << 16);   // RNE both halves
}
__device__ __forceinline__ f32x4 mfma16(s16x8 a, s16x8 b, f32x4 c) {
    return __builtin_amdgcn_mfma_f32_16x16x32_bf16(a, b, c, 0, 0, 0);
}
__device__ __forceinline__ f32x16 mfma32(s16x8 a, s16x8 b, f32x16 c) {
    return __builtin_amdgcn_mfma_f32_32x32x16_bf16(a, b, c, 0, 0, 0);
}
__device__ __forceinline__ void async16(const void* g, void* l) {
    __builtin_amdgcn_global_load_lds(
        (const __attribute__((address_space(1))) void*)g,
        (__attribute__((address_space(3))) void*)l, 16, 0, 0);
}

#define ROPE_C (-13.287712379549449f / 32.0f)

// ---------------------------------------------------------------------------
// fp32 -> bf16: x -> xb, wq|wk|wv -> wqkvb, wp -> wpb.
// ---------------------------------------------------------------------------
__global__ __launch_bounds__(256) void convert_all(
    const float* __restrict__ x,  const float* __restrict__ wq,
    const float* __restrict__ wk, const float* __restrict__ wv,
    const float* __restrict__ wp,
    unsigned short* __restrict__ xb, unsigned short* __restrict__ wqkvb,
    unsigned short* __restrict__ wpb)
{
    const size_t XN = 2048u * 1024u, WN = 1024u * 1024u;
    size_t e = ((size_t)blockIdx.x * 256 + threadIdx.x) * 4;
    const float* s; unsigned short* d;
    if (e < XN)                { s = x  + e;               d = xb    + e; }
    else if (e < XN + WN)      { s = wq + (e - XN);        d = wqkvb + (e - XN); }
    else if (e < XN + 2 * WN)  { s = wk + (e - XN - WN);   d = wqkvb + (e - XN); }
    else if (e < XN + 3 * WN)  { s = wv + (e - XN - 2*WN); d = wqkvb + (e - XN); }
    else                       { s = wp + (e - XN - 3*WN); d = wpb   + (e - XN - 3*WN); }
    float4 v = *(const float4*)s;
    ushort4 o;
    o.x = f2bf(v.x); o.y = f2bf(v.y); o.z = f2bf(v.z); o.w = f2bf(v.w);
    *(ushort4*)d = o;
}

// ---------------------------------------------------------------------------
// bf16 GEMM (m97 structure): C = A[M x 1024] * B[N x 1024]^T.
// BM x BN tile, 4 waves (2x2), wave tile (BM/2)x(BN/2), global_load_lds.
// 1D grid, XCD-aware decode (R11, neutral; kept):
//   bx = (bid&7)*CX + (bid>>3)%CX ; by = (bid>>3)/CX ; CX = GX/8.
//
// BK=64 IS THE OPERATING POINT (R15): BK=128 measured +18us — bigger
// vmcnt(0) drains per barrier + qkv LDS 24->48KB occupancy loss beat the
// barrier-amortization gain. m132's lesson generalizes to this structure.
//
// *** RoPE binding order IS CORRECT AS WRITTEN — do not "fix" it. ***
// __sincosf(ang,&c,&s) binds c=sin(ang), s=cos(ang); the update is
// R(theta - pi/2) — reference rotation composed with a CONSTANT 90-degree
// rotation. Applied identically to q and k, the relative rotation
// R(th_n - th_m) (all logits see) matches the reference exactly.
// Binding sin-first gives the INVERSE relative rotation (R4 fail, 2.9e-2).
//
// Q-prescale: q section (n0<1024) scaled by 0.125 = 2^-3 (exact in bf16 ->
// attn exp argument BIT-IDENTICAL); removes *0.125f from attn hot loop.
// (R9/R10: transposed-V epilogue FAILED twice — abandoned.)
// NOTE (R3): 128x128 tile starves the grid at this shape — 64x128 is right.
// ---------------------------------------------------------------------------
template<int BM, int BN, int BK, int C32, int ROPE, int GX>
__global__ __launch_bounds__(256) void gemm_mfma(
    const unsigned short* __restrict__ A,
    const unsigned short* __restrict__ B,
    void* __restrict__ C, int Ntot)
{
    constexpr int MT = BM / 32, NT = BN / 32;
    constexpr int CX = GX / 8;
    constexpr int RPL = 512 / BK;            // rows per wave-load
    constexpr int LA  = BM / RPL;            // wave-loads for A per k-step
    constexpr int LB  = BN / RPL;
    __shared__ unsigned short As[BM * BK];
    __shared__ unsigned short Bs[BN * BK];

    const int bid  = blockIdx.x;
    const int bx   = (bid & 7) * CX + ((bid >> 3) % CX);
    const int by   = (bid >> 3) / CX;

    const int tid  = threadIdx.x;
    const int wave = tid >> 6, lane = tid & 63;
    const int l16  = lane & 15, quad = lane >> 4;
    const int m0   = by * BM, n0 = bx * BN;
    const int wm   = (wave & 1) * (BM / 2), wn = (wave >> 1) * (BN / 2);

    const int srow = lane / (BK / 8);        // 0..RPL-1
    const int scol = (lane % (BK / 8)) * 8;  // 0..BK-8

    f32x4 acc[MT][NT] = {};

    for (int k0 = 0; k0 < 1024; k0 += BK) {
        #pragma unroll
        for (int i = 0; i < LA / 4; i++) {
            int j = wave * (LA / 4) + i;
            async16(A + (size_t)(m0 + j * RPL + srow) * 1024 + k0 + scol, &As[j * 512]);
        }
        #pragma unroll
        for (int i = 0; i < LB / 4; i++) {
            int j = wave * (LB / 4) + i;
            async16(B + (size_t)(n0 + j * RPL + srow) * 1024 + k0 + scol, &Bs[j * 512]);
        }
        __syncthreads();

        #pragma unroll
        for (int ks = 0; ks < BK / 32; ks++) {
            s16x8 af[MT], bfr[NT];
            #pragma unroll
            for (int mt = 0; mt < MT; mt++)
                af[mt] = *(const s16x8*)&As[(wm + mt * 16 + l16) * BK + ks * 32 + quad * 8];
            #pragma unroll
            for (int nt = 0; nt < NT; nt++)
                bfr[nt] = *(const s16x8*)&Bs[(wn + nt * 16 + l16) * BK + ks * 32 + quad * 8];
            #pragma unroll
            for (int mt = 0; mt < MT; mt++)
                #pragma unroll
                for (int nt = 0; nt < NT; nt++)
                    acc[mt][nt] = mfma16(af[mt], bfr[nt], acc[mt][nt]);
        }
        __syncthreads();
    }

    // Fused RoPE on q/k sections (in-register, fp32, before bf16 store)
    if constexpr (ROPE) {
        if (n0 < 2048) {
            const float sc = (n0 < 1024) ? 0.125f : 1.0f;   // Q-prescale
            #pragma unroll
            for (int mt = 0; mt < MT; mt++)
                #pragma unroll
                for (int r = 0; r < 4; r++) {
                    int m = m0 + wm + mt * 16 + quad * 4 + r;   // token
                    #pragma unroll
                    for (int nt = 0; nt < 2; nt++) {
                        int i = nt * 16 + l16;                  // 0..31 in head
                        float ang = (float)m * exp2f((float)i * ROPE_C);
                        float c, s;
                        __sincosf(ang, &c, &s);   // c=sin, s=cos — see header note
                        c *= sc; s *= sc;
                        float e0 = acc[mt][nt][r], e1 = acc[mt][nt + 2][r];
                        acc[mt][nt][r]     = e0 * c + e1 * s;
                        acc[mt][nt + 2][r] = e1 * c - e0 * s;
                    }
                }
        }
    }

    // C/D layout: col = lane&15, row = quad*4 + reg
    #pragma unroll
    for (int mt = 0; mt < MT; mt++)
        #pragma unroll
        for (int nt = 0; nt < NT; nt++)
            #pragma unroll
            for (int r = 0; r < 4; r++) {
                int m = m0 + wm + mt * 16 + quad * 4 + r;
                int n = n0 + wn + nt * 16 + l16;
                size_t idx = (size_t)m * Ntot + n;
                if (C32) ((float*)C)[idx] = acc[mt][nt][r];
                else     ((unsigned short*)C)[idx] = f2bf(acc[mt][nt][r]);
            }
}

// ---------------------------------------------------------------------------
// Split-K flash attention, 32x32x16 MFMA, operand-swapped QK (verified r12).
// 1024 blocks, XCD-swizzled 1D grid (R8-proven): 16 q-blocks sharing one
// (head,ksplit) slice -> same XCD -> per-XCD L2 working set ~1MB << 4MB.
// K via global_load_lds (R12): async DMA, dbuf, linear dest + pre-swizzled
// GLOBAL source chunk (l&7)^(l>>3), reads XOR the same — rule #21.
// V via prefetched reg-gather (R13): issue V(t+1) before compute(t), pinned
// by sched_barrier(0); commit after barrier A (its vmcnt-drain covers it).
// P never touches LDS (T12). f2bf RNE mandatory (cvt_pk truncates, R2).
// Q pre-scaled by 0.125 in qkv GEMM. T5 setprio kept (neutral).
// ---------------------------------------------------------------------------
__global__ __launch_bounds__(256, 4) void attn_part(
    const unsigned short* __restrict__ qkv,
    unsigned short* __restrict__ Opart, float* __restrict__ Lpart)
{
    const int bid    = blockIdx.x;
    const int member = (bid >> 3) & 15;
    const int slice  = (bid & 7) + 8 * (bid >> 7);
    const int h  = slice & 15;
    const int ks = slice >> 4;
    const int q0 = member * 128;

    const int tid  = threadIdx.x;
    const int wave = tid >> 6, lane = tid & 63;
    const int l32  = lane & 31, half = lane >> 5;

    __shared__ unsigned short Ks[2][64][64];   // [buf][key][chunk-swizzled d]
    __shared__ unsigned short Vt[64][72];      // [d][key] pad-72

    const int srow8 = lane >> 3;                 // 0..7
    const int csw   = ((lane & 7) ^ srow8) * 8;  // pre-swizzled source chunk

    auto stageK = [&](int t, int p) {
        const int kt = ks * 512 + t * 64;
        #pragma unroll
        for (int i = 0; i < 2; i++) {
            int rb = wave * 2 + i;               // row-block 0..7
            async16(qkv + (size_t)(kt + rb * 8 + srow8) * 3072 + 1024 + h * 64 + csw,
                    &Ks[p][rb * 8][0]);
        }
    };

    // V gather across all 256 threads: 2 keys x 8 d-elements each
    const int vg  = tid & 31;                    // key-pair index (keys 2vg, 2vg+1)
    const int vd0 = (tid >> 5) * 8;              // 8-d block
    uint4 vr0, vr1;
    auto issueV = [&](int t) {
        const unsigned short* gv = qkv + (size_t)(ks * 512 + t * 64 + 2 * vg) * 3072
                                       + 2048 + h * 64 + vd0;
        vr0 = *(const uint4*)gv;
        vr1 = *(const uint4*)(gv + 3072);
    };
    auto commitV = [&]() {
        unsigned short a0[8], a1[8];
        *(uint4*)a0 = vr0; *(uint4*)a1 = vr1;
        #pragma unroll
        for (int d = 0; d < 8; d++) {
            ushort2 w; w.x = a0[d]; w.y = a1[d];
            *(ushort2*)&Vt[vd0 + d][2 * vg] = w;  // 2-way bank alias (free, m136)
        }
    };

    stageK(0, 0);                                // K-DMA(0) in flight
    issueV(0);

    const unsigned short* qp = qkv + (size_t)(q0 + wave * 32 + l32) * 3072 + h * 64 + half * 8;
    s16x8 qb[4];
    #pragma unroll
    for (int c = 0; c < 4; c++)
        qb[c] = *(const s16x8*)(qp + c * 16);

    commitV();                                   // auto-waits V(0) loads
    f32x16 o0 = {}, o1 = {};
    float lsum = 0.f;

    __syncthreads();                             // Ks[0] + Vt(0) ready

    for (int t = 0; t < 8; t++) {
        const int p = t & 1;
        if (t < 7) {
            stageK(t + 1, p ^ 1);                // async DMA under compute(t)
            issueV(t + 1);                       // reg loads under compute(t)
            __builtin_amdgcn_sched_barrier(0);   // pin: no sinking past here
        }

        #pragma unroll
        for (int g = 0; g < 2; g++) {
            f32x16 s = {};
            __builtin_amdgcn_s_setprio(1);
            #pragma unroll
            for (int c = 0; c < 4; c++) {
                int row = g * 32 + l32;
                int ch  = ((c * 2 + half) ^ (row & 7)) * 8;   // swizzled read
                s16x8 ka = *(const s16x8*)&Ks[p][row][ch];
                s = mfma32(ka, qb[c], s);
            }
            __builtin_amdgcn_s_setprio(0);
            #pragma unroll
            for (int f = 0; f < 2; f++) {
                float e[8];
                #pragma unroll
                for (int j = 0; j < 8; j++) {
                    e[j] = __expf(s[8 * f + j]);   // scale folded into Q
                    lsum += e[j];
                }
                // RNE-packed pairs (bit-identical P to LDS baseline)
                unsigned w0 = pack2bf(e[0], e[1]);   // lo0
                unsigned w1 = pack2bf(e[2], e[3]);   // lo1
                unsigned w2 = pack2bf(e[4], e[5]);   // hi0
                unsigned w3 = pack2bf(e[6], e[7]);   // hi1
                // DST=lo, SRC=hi: dst'=word0/1, src'=word2/3
                asm("v_permlane32_swap_b32 %0, %1" : "+v"(w0), "+v"(w2));
                asm("v_permlane32_swap_b32 %0, %1" : "+v"(w1), "+v"(w3));
                u32x4 wv; wv.x = w0; wv.y = w1; wv.z = w2; wv.w = w3;
                s16x8 pa = __builtin_bit_cast(s16x8, wv);
                const int c = 2 * g + f;
                s16x8 v0 = *(const s16x8*)&Vt[l32][c * 16 + half * 8];
                s16x8 v1 = *(const s16x8*)&Vt[32 + l32][c * 16 + half * 8];
                __builtin_amdgcn_s_setprio(1);
                o0 = mfma32(pa, v0, o0);
                o1 = mfma32(pa, v1, o1);
                __builtin_amdgcn_s_setprio(0);
            }
        }

        __syncthreads();          // (A) all read Vt(t); drains K-DMA + V-loads
        if (t < 7) {
            commitV();            // Vt(t+1), no extra wait needed
            __syncthreads();      // (B) Vt(t+1) visible to all
        }
    }

    lsum += __shfl_xor(lsum, 32, 64);

    const int mq = q0 + wave * 32;
    unsigned short* opBase = Opart + (size_t)ks * 2048 * 1024;
    #pragma unroll
    for (int r = 0; r < 16; r++) {
        int qr = (r & 3) + 8 * (r >> 2) + 4 * half;
        unsigned short* op = opBase + (size_t)(mq + qr) * 1024 + h * 64;
        op[l32]      = f2bf(o0[r]);
        op[32 + l32] = f2bf(o1[r]);
    }
    if (half == 0)
        Lpart[((size_t)ks * 2048 + mq + l32) * 16 + h] = lsum;
}

// ---------------------------------------------------------------------------
// Combine 4 bf16 split-K partials: ab = (sum n_i) / (sum l_i), bf16.
// ---------------------------------------------------------------------------
__global__ __launch_bounds__(256) void combine(
    const unsigned short* __restrict__ Opart, const float* __restrict__ Lpart,
    unsigned short* __restrict__ ab)
{
    size_t e = ((size_t)blockIdx.x * 256 + threadIdx.x) * 4;
    int tok = (int)(e >> 10);
    int h = (int)((e & 1023) >> 6);
    float l = 0.f;
    #pragma unroll
    for (int s = 0; s < 4; s++)
        l += Lpart[((size_t)s * 2048 + tok) * 16 + h];
    float inv = 1.0f / l;
    float a0 = 0.f, a1 = 0.f, a2 = 0.f, a3 = 0.f;
    #pragma unroll
    for (int s = 0; s < 4; s++) {
        ushort4 n = *(const ushort4*)(Opart + (size_t)s * 2048 * 1024 + e);
        a0 += bf2f(n.x); a1 += bf2f(n.y); a2 += bf2f(n.z); a3 += bf2f(n.w);
    }
    ushort4 w;
    w.x = f2bf(a0 * inv);
    w.y = f2bf(a1 * inv);
    w.z = f2bf(a2 * inv);
    w.w = f2bf(a3 * inv);
    *(ushort4*)(ab + e) = w;
}

extern "C" void kernel_launch(void* const* d_in, const int* in_sizes, int n_in,
                              void* d_out, int out_size, void* d_ws, size_t ws_size,
                              hipStream_t stream)
{
    const float* x  = (const float*)d_in[0];
    const float* wq = (const float*)d_in[1];
    const float* wk = (const float*)d_in[2];
    const float* wv = (const float*)d_in[3];
    const float* wp = (const float*)d_in[4];

    unsigned short* xb    = (unsigned short*)d_ws;        // 2M shorts
    unsigned short* wqkvb = xb    + 2u * 1024 * 1024;     // 3M
    unsigned short* wpb   = wqkvb + 3u * 1024 * 1024;     // 1M
    unsigned short* qkv   = wpb   + 1u * 1024 * 1024;     // 6M
    unsigned short* ab    = qkv   + 2048u * 3072;         // 2M
    unsigned short* Opart = ab    + 2u * 1024 * 1024;     // 4 x 2048 x 1024 bf16
    float* Lpart = (float*)(Opart + 4u * 2048 * 1024);    // 4 x 2048 x 16 fp32

    convert_all<<<6144, 256, 0, stream>>>(x, wq, wk, wv, wp, xb, wqkvb, wpb);
    // qkv GEMM with fused RoPE: 64x128 tile, BK=64 (R15: BK=128 regresses),
    // 1D XCD-swizzled grid of 768
    gemm_mfma<64, 128, 64, 0, 1, 24><<<768, 256, 0, stream>>>(
        xb, wqkvb, qkv, 3072);
    // attn: 1D XCD-swizzled grid; K via swizzled-source DMA dbuf,
    // V via prefetched reg-gather (sched_barrier-pinned)
    attn_part<<<1024, 256, 0, stream>>>(qkv, Opart, Lpart);
    combine<<<2048, 256, 0, stream>>>(Opart, Lpart, ab);
    // proj: 64x64 tile, BK=64, 1D XCD-swizzled grid of 512, fp32 out
    gemm_mfma<64, 64, 64, 1, 0, 16><<<512, 256, 0, stream>>>(
        ab, wpb, d_out, 1024);
}